// Round 6
// baseline (170.797 us; speedup 1.0000x reference)
//
#include <hip/hip_runtime.h>
#include <hip/hip_bf16.h>

// Problem constants
#define AG 8
#define BT 2048
#define RT (AG*BT)      // 16384 rows
#define NNET 4
#define D0 128
#define H1 1024
#define H2 1024
#define H3 512

typedef __attribute__((ext_vector_type(8))) short short8;
typedef __attribute__((ext_vector_type(4))) float f32x4;

__device__ __forceinline__ float bf2f(unsigned short u){
  return __uint_as_float(((unsigned int)u) << 16);
}
__device__ __forceinline__ unsigned short f2bf(float f){
  unsigned int x = __float_as_uint(f);
  x += 0x7fff + ((x >> 16) & 1);   // RNE
  return (unsigned short)(x >> 16);
}

template<int N> __device__ __forceinline__ void vmw(){
  if constexpr (N==8)      asm volatile("s_waitcnt vmcnt(8)" ::: "memory");
  else if constexpr (N==6) asm volatile("s_waitcnt vmcnt(6)" ::: "memory");
  else if constexpr (N==4) asm volatile("s_waitcnt vmcnt(4)" ::: "memory");
  else if constexpr (N==3) asm volatile("s_waitcnt vmcnt(3)" ::: "memory");
  else                     asm volatile("s_waitcnt vmcnt(0)" ::: "memory");
}

__device__ __forceinline__ void gload_lds16(const void* g, void* l){
  __builtin_amdgcn_global_load_lds(
      (const __attribute__((address_space(1))) unsigned int*)g,
      (__attribute__((address_space(3))) unsigned int*)l, 16, 0, 0);
}

// exclusive prefix of counts[0..n-1]
__device__ __forceinline__ int bucket_off(const int* counts, int n){
  int s = 0;
  #pragma unroll
  for (int i = 0; i < NNET-1; i++) if (i < n) s += counts[i];
  return s;
}

__global__ void k_init(int* counts){
  if (threadIdx.x < NNET) counts[threadIdx.x] = 0;
}

// Hierarchical compaction: LDS-local rank + one global atomicAdd per (block,net).
__global__ __launch_bounds__(256) void k_compact(const int* __restrict__ seps,
                          int* __restrict__ counts, int* __restrict__ rowlist){
  __shared__ int lcount[NNET];
  __shared__ int lbase[NNET];
  int t = blockIdx.x * 256 + threadIdx.x;
  if (threadIdx.x < NNET) lcount[threadIdx.x] = 0;
  __syncthreads();
  int a = t >> 11, b = t & (BT-1);      // row t == (a,b)
  int n = seps[b*AG + a];               // seps_indices is [B,A]
  int lrank = atomicAdd(&lcount[n], 1);
  __syncthreads();
  if (threadIdx.x < NNET)
    lbase[threadIdx.x] = atomicAdd(&counts[threadIdx.x], lcount[threadIdx.x]);
  __syncthreads();
  rowlist[n*RT + lbase[n] + lrank] = t;
}

// W[n][K][NOUT] f32 -> WT[n][NOUT][K] bf16
template<int K, int NOUT>
__global__ __launch_bounds__(256) void k_transpose(const float* __restrict__ W,
                                                   unsigned short* __restrict__ WT){
  __shared__ float tile[32][33];
  int n = blockIdx.z;
  int k0 = blockIdx.x*32, o0 = blockIdx.y*32;
  const float* Wn = W + (size_t)n*K*NOUT;
  unsigned short* WTn = WT + (size_t)n*NOUT*K;
  int tx = threadIdx.x & 31, ty0 = threadIdx.x >> 5;
  #pragma unroll
  for (int r = 0; r < 32; r += 8)
    tile[ty0 + r][tx] = Wn[(size_t)(k0 + ty0 + r)*NOUT + o0 + tx];
  __syncthreads();
  #pragma unroll
  for (int r = 0; r < 32; r += 8)
    WTn[(size_t)(o0 + ty0 + r)*K + k0 + tx] = f2bf(tile[tx][ty0 + r]);
}

// gather fp32 input rows -> compacted bf16 X0h[RT][D0]
__global__ __launch_bounds__(256) void k_gather0(const float* __restrict__ X,
                          const int* __restrict__ counts,
                          const int* __restrict__ rowlist, unsigned short* __restrict__ X0h){
  int n = blockIdx.y;
  int cnt = counts[n];
  int i = blockIdx.x*16 + (threadIdx.x >> 4);
  if (i >= cnt) return;
  int off = bucket_off(counts, n);
  int orig = rowlist[n*RT + i];
  int c = (threadIdx.x & 15) * 8;
  const float* src = X + (size_t)orig*D0 + c;
  float4 v0 = *(const float4*)src, v1 = *(const float4*)(src+4);
  ushort4 u0, u1;
  u0.x=f2bf(v0.x); u0.y=f2bf(v0.y); u0.z=f2bf(v0.z); u0.w=f2bf(v0.w);
  u1.x=f2bf(v1.x); u1.y=f2bf(v1.y); u1.z=f2bf(v1.z); u1.w=f2bf(v1.w);
  unsigned short* dst = X0h + (size_t)(off + i)*D0 + c;
  *(ushort4*)dst = u0; *(ushort4*)(dst+4) = u1;
}

// MFMA GEMM over one network bucket: C[rows, NOUT] = X[rows,K] * WT[NOUT,K]^T + bias
// BM=256, BN=256 or 128, BK=32, 512 threads (8 waves, WMW x WNW), wave-tile
// (256/WMW) x (BN/WNW), 16x16x32 bf16 MFMA, swapped operands (lane's 4 acc
// regs = 4 consecutive output cols -> float4/ushort4 stores).
// R5-proven sync skeleton (parameter-lane change only): 3 LDS buffers,
// counted s_waitcnt vmcnt (never 0 in steady state), raw s_barriers,
// lgkmcnt(0)+sched_barrier(0) fence (rule #18), re-issue step ks+3 after the
// second barrier, MFMA under setprio.
// 16B-slot XOR swizzle (slot ^= (row>>1)&3) on BOTH global source and ds_read.
template<int K, int NOUT, int BN, int WMW, int WNW, int RELU, int SCATTER>
__global__ __launch_bounds__(512) void k_mlp(
    const unsigned short* __restrict__ X,   // compacted bf16 [RT, K]
    const unsigned short* __restrict__ WT,  // [N, NOUT, K] bf16
    const float* __restrict__ Bias,         // [N, NOUT] f32
    const int* __restrict__ counts,
    const int* __restrict__ rowlist,
    unsigned short* __restrict__ Yh,        // compacted bf16 out
    float* __restrict__ Yf)                 // scatter f32 out
{
  constexpr int T  = K / 32;                // K-steps
  constexpr int MF = 256 / WMW / 16;        // A-frags per wave (8 or 4)
  constexpr int NF = BN  / WNW / 16;        // B-frags per wave (4)
  constexpr int LA = 2;                     // A-loads per thread per step
  constexpr int LB = (BN*32*2) / (512*16);  // B-loads (2 for BN=256, 1 for 128)
  constexpr int LPT = LA + LB;

  const int n = blockIdx.z;
  const int cnt = counts[n];
  const int i0 = blockIdx.x * 256;
  if (i0 >= cnt) return;
  const int off = bucket_off(counts, n);
  const int bn = blockIdx.y * BN;

  __shared__ __align__(16) unsigned short As[3][256*32];
  __shared__ __align__(16) unsigned short Bs[3][BN*32];
  __shared__ int rs[256];

  const int t = threadIdx.x, lane = t & 63, wave = t >> 6;
  const int wm = wave / WNW, wn = wave % WNW;
  const int lr = lane & 15, g = lane >> 4;

  if (SCATTER && t < 256) rs[t] = rowlist[n*RT + min(i0 + t, cnt-1)];

  // staging: A tile 256x32 bf16 (16KB) = 1024 16B-slots; B tile BN*32 bf16.
  // slot-id s = j*512 + t -> row = s>>2, phys slot = s&3; global src uses the
  // inverse-swizzled logical slot so swizzled ds_reads see the right data.
  const unsigned short* pA[LA]; const unsigned short* pB[LB];
  unsigned int loffA[LA], loffB[LB];
  const unsigned short* WTn = WT + (size_t)n * NOUT * K;
  #pragma unroll
  for (int j = 0; j < LA; j++){
    int s = j*512 + t, r = s >> 2;
    int ls = (s & 3) ^ ((r >> 1) & 3);
    pA[j] = X + (size_t)(off + min(i0 + r, cnt-1))*K + ls*8;
    loffA[j] = (unsigned)s * 8;
  }
  #pragma unroll
  for (int j = 0; j < LB; j++){
    int s = j*512 + t, r = s >> 2;
    int ls = (s & 3) ^ ((r >> 1) & 3);
    pB[j] = WTn + (size_t)(bn + r)*K + ls*8;
    loffB[j] = (unsigned)s * 8;
  }

  // fragment ds_read offsets (swizzled)
  int aoff[MF], boff[NF];
  #pragma unroll
  for (int i = 0; i < MF; i++){
    int ra = wm*(MF*16) + i*16 + lr;
    aoff[i] = ra*32 + (g ^ ((ra>>1)&3))*8;
  }
  #pragma unroll
  for (int i = 0; i < NF; i++){
    int rb = wn*(NF*16) + i*16 + lr;
    boff[i] = rb*32 + (g ^ ((rb>>1)&3))*8;
  }

  __syncthreads();   // rs visible; clean start before async issues

  // prologue: issue K-steps 0..2 into buffers 0..2 (3*LPT loads/thread in flight)
  #pragma unroll
  for (int s = 0; s < 3; ++s){
    #pragma unroll
    for (int j = 0; j < LA; j++){ gload_lds16(pA[j], &As[s][loffA[j]]); pA[j] += 32; }
    #pragma unroll
    for (int j = 0; j < LB; j++){ gload_lds16(pB[j], &Bs[s][loffB[j]]); pB[j] += 32; }
  }

  f32x4 acc[MF][NF] = {};
  int b = 0;
  for (int ks = 0; ks < T; ++ks){
    // wait for buffer b's loads (oldest LPT); keep later 2*LPT in flight
    if (ks < T-2)       vmw<2*LPT>();
    else if (ks == T-2) vmw<LPT>();
    else                vmw<0>();
    __builtin_amdgcn_s_barrier();          // buf b populated for all waves

    short8 av[MF], bv[NF];
    #pragma unroll
    for (int i = 0; i < MF; i++) av[i] = *(const short8*)&As[b][aoff[i]];
    #pragma unroll
    for (int i = 0; i < NF; i++) bv[i] = *(const short8*)&Bs[b][boff[i]];
    asm volatile("s_waitcnt lgkmcnt(0)" ::: "memory");
    __builtin_amdgcn_sched_barrier(0);     // rule #18: pin MFMA below the wait
    __builtin_amdgcn_s_barrier();          // all waves done reading buf b

    if (ks + 3 < T){                       // re-issue step ks+3 into same buf b
      #pragma unroll
      for (int j = 0; j < LA; j++){ gload_lds16(pA[j], &As[b][loffA[j]]); pA[j] += 32; }
      #pragma unroll
      for (int j = 0; j < LB; j++){ gload_lds16(pB[j], &Bs[b][loffB[j]]); pB[j] += 32; }
    }

    __builtin_amdgcn_s_setprio(1);
    #pragma unroll
    for (int mi = 0; mi < MF; mi++)
      #pragma unroll
      for (int ni = 0; ni < NF; ni++)
        acc[mi][ni] = __builtin_amdgcn_mfma_f32_16x16x32_bf16(bv[ni], av[mi], acc[mi][ni], 0, 0, 0);
    __builtin_amdgcn_s_setprio(0);

    b = (b == 2) ? 0 : b + 1;
  }

  // epilogue (swapped field-map): lane's reg i = output col (ni*16 + g*4 + i),
  // output row = wm*MF*16 + mi*16 + lr.  Bias as float4, stores float4/ushort4.
  f32x4 bias4[NF];
  #pragma unroll
  for (int ni = 0; ni < NF; ni++)
    bias4[ni] = *(const f32x4*)&Bias[n*NOUT + bn + wn*(NF*16) + ni*16 + (g<<2)];

  #pragma unroll
  for (int mi = 0; mi < MF; mi++){
    int rloc = wm*(MF*16) + mi*16 + lr;
    int grow = i0 + rloc;
    if (grow < cnt){
      #pragma unroll
      for (int ni = 0; ni < NF; ni++){
        float o[4];
        #pragma unroll
        for (int i = 0; i < 4; i++){
          float v = acc[mi][ni][i] + bias4[ni][i];
          if (RELU) v = fmaxf(v, 0.f);
          o[i] = v;
        }
        int cb = bn + wn*(NF*16) + ni*16 + (g<<2);
        if (SCATTER){
          *(float4*)&Yf[(size_t)rs[rloc]*NOUT + cb] = make_float4(o[0],o[1],o[2],o[3]);
        } else {
          ushort4 u;
          u.x=f2bf(o[0]); u.y=f2bf(o[1]); u.z=f2bf(o[2]); u.w=f2bf(o[3]);
          *(ushort4*)&Yh[(size_t)(off + grow)*NOUT + cb] = u;
        }
      }
    }
  }
}

extern "C" void kernel_launch(void* const* d_in, const int* in_sizes, int n_in,
                              void* d_out, int out_size, void* d_ws, size_t ws_size,
                              hipStream_t stream) {
  const float* inputs = (const float*)d_in[0];
  const int*   seps   = (const int*)  d_in[1];
  const float* W0     = (const float*)d_in[2];
  const float* b0     = (const float*)d_in[3];
  const float* W1     = (const float*)d_in[4];
  const float* b1     = (const float*)d_in[5];
  const float* W2     = (const float*)d_in[6];
  const float* b2     = (const float*)d_in[7];
  float* out = (float*)d_out;

  // ws layout (78 MiB):
  // 0: counts | 4K: rowlist(256K) | 1M: WT0(1M) | 2M: WT1(8M) | 10M: WT2(4M)
  // 14M: h1(32M) | 46M: h2(32M), X0h(4M) overlaps h2 start (disjoint lifetimes)
  char* ws = (char*)d_ws;
  int* counts  = (int*)ws;
  int* rowlist = (int*)(ws + 4096);
  const size_t MB = 1u << 20;
  unsigned short* WT0 = (unsigned short*)(ws + 1*MB);
  unsigned short* WT1 = (unsigned short*)(ws + 2*MB);
  unsigned short* WT2 = (unsigned short*)(ws + 10*MB);
  unsigned short* h1  = (unsigned short*)(ws + 14*MB);
  unsigned short* h2  = (unsigned short*)(ws + 46*MB);
  unsigned short* X0h = (unsigned short*)(ws + 46*MB);  // dead before h2 written

  k_init   <<<1, 64, 0, stream>>>(counts);
  k_compact<<<RT/256, 256, 0, stream>>>(seps, counts, rowlist);

  k_transpose<D0, H1><<<dim3(D0/32, H1/32, NNET), 256, 0, stream>>>(W0, WT0);
  k_transpose<H1, H2><<<dim3(H1/32, H2/32, NNET), 256, 0, stream>>>(W1, WT1);
  k_transpose<H2, H3><<<dim3(H2/32, H3/32, NNET), 256, 0, stream>>>(W2, WT2);
  k_gather0<<<dim3(RT/16, NNET), 256, 0, stream>>>(inputs, counts, rowlist, X0h);

  // Layer 0: BN=256, waves 2x4 (wave-tile 128x64)
  k_mlp<D0, H1, 256, 2, 4, 1, 0><<<dim3(RT/256, H1/256, NNET), 512, 0, stream>>>(
      X0h, WT0, b0, counts, rowlist, h1, nullptr);
  // Layer 1: BN=256, waves 2x4
  k_mlp<H1, H2, 256, 2, 4, 1, 0><<<dim3(RT/256, H2/256, NNET), 512, 0, stream>>>(
      h1, WT1, b1, counts, rowlist, h2, nullptr);
  // Layer 2: BN=128, waves 4x2 (wave-tile 64x64), scatter f32
  k_mlp<H2, H3, 128, 4, 2, 0, 1><<<dim3(RT/256, H3/128, NNET), 512, 0, stream>>>(
      h2, WT2, b2, counts, rowlist, nullptr, out);
}